// Round 2
// baseline (162.413 us; speedup 1.0000x reference)
//
#include <hip/hip_runtime.h>
#include <hip/hip_bf16.h>

#define IMG 256
#define TS 20

typedef unsigned short u16;
typedef __bf16 bf16x8 __attribute__((ext_vector_type(8)));
typedef float f32x4 __attribute__((ext_vector_type(4)));
typedef unsigned short ushort8 __attribute__((ext_vector_type(8)));

__device__ __forceinline__ double cc1d(double x) {
    const double A = -0.75;
    return ((A + 2.0) * x - (A + 3.0)) * x * x + 1.0;
}
__device__ __forceinline__ double cc2d(double x) {
    const double A = -0.75;
    return ((A * x - 5.0 * A) * x + 8.0 * A) * x - 4.0 * A;
}

// fp32 -> bf16 round-to-nearest-even, bit form
__device__ __forceinline__ u16 f2bf(float f) {
    unsigned u = __float_as_uint(f);
    u = u + 0x7fffu + ((u >> 16) & 1u);
    return (u16)(u >> 16);
}

// ---------------------------------------------------------------------------
// Kernel 1: build P_t = M_{t-1} ... M_0 (bf16, row-major), one block per (o,t).
// ---------------------------------------------------------------------------
__global__ void build_P(u16* __restrict__ Pbf) {
    __shared__ float v[2][IMG];
    const int o = blockIdx.x;
    const int t = blockIdx.y;
    const int h = threadIdx.x;

    v[0][h] = (h == o) ? 1.0f : 0.0f;
    int cur = 0;
    __syncthreads();

    for (int i = t - 1; i >= 0; --i) {
        const int nxt = cur ^ 1;
        const float val = v[cur][h];
        v[nxt][h] = 0.0f;
        __syncthreads();
        if (val != 0.0f) {
            const int s = IMG - i;
            double xs = (h + 0.5) * (double)s / 256.0;
            int j = (int)xs;
            if (j > s - 1) j = s - 1;
            double x = (j + 0.5) * 256.0 / (double)s - 0.5;
            int i0 = (int)floor(x);
            double tt = x - (double)i0;
            double w[4] = {cc2d(tt + 1.0), cc1d(tt), cc1d(1.0 - tt), cc2d(2.0 - tt)};
#pragma unroll
            for (int k = 0; k < 4; ++k) {
                int c = i0 - 1 + k;
                c = min(max(c, 0), IMG - 1);
                atomicAdd(&v[nxt][c], val * (float)w[k]);
            }
        }
        __syncthreads();
        cur = nxt;
    }
    Pbf[((size_t)t * IMG + o) * IMG + h] = f2bf(v[cur][h]);
}

// ---------------------------------------------------------------------------
// Fused kernel: one block per (b,c) image.
//   stage:  X fp32 (global) -> bf16 LDS [h][w]   (XOR-swizzled 16B chunks)
//   gemm1:  Zt[p][h] = sum_w P[p][w] * X[h][w]    (A=P global/L2, Bt=X LDS)
//   write:  Zt bf16 -> same LDS buffer [p][h]     (swizzled)
//   gemm2:  out[o][p] = sum_h P[o][h] * Zt[p][h]  (A=P global/L2, Bt=Zt LDS)
// ---------------------------------------------------------------------------
__global__ __launch_bounds__(512, 2) void fused_pxp(const u16* __restrict__ Pbf,
                                                    const float* __restrict__ X,
                                                    float* __restrict__ out,
                                                    const int* __restrict__ tarr) {
    __shared__ __align__(16) u16 lds[IMG * IMG];  // 128 KB

    const int bc = blockIdx.x;
    const int b = bc / 3;
    const int tsel = tarr[b];
    const u16* __restrict__ P = Pbf + (size_t)tsel * IMG * IMG;
    const float* __restrict__ Xb = X + (size_t)bc * IMG * IMG;
    float* __restrict__ outb = out + (size_t)bc * IMG * IMG;

    const int tid = threadIdx.x;
    const int lane = tid & 63;
    const int wave = tid >> 6;
    const int wm = (wave >> 2) * 128;
    const int wn = (wave & 3) * 64;
    const int l15 = lane & 15;
    const int lhi = lane >> 4;
    const int row4 = lhi * 4;

    // ---- stage X ----
#pragma unroll
    for (int it = 0; it < 16; ++it) {
        const int g = it * 512 + tid;
        const int h = g >> 5;
        const int c = g & 31;
        const float* src = Xb + (size_t)h * IMG + c * 8;
        const float4 v0 = *(const float4*)(src);
        const float4 v1 = *(const float4*)(src + 4);
        ushort8 pk;
        pk[0] = f2bf(v0.x); pk[1] = f2bf(v0.y); pk[2] = f2bf(v0.z); pk[3] = f2bf(v0.w);
        pk[4] = f2bf(v1.x); pk[5] = f2bf(v1.y); pk[6] = f2bf(v1.z); pk[7] = f2bf(v1.w);
        *(ushort8*)(&lds[h * IMG + ((c ^ (h & 7)) * 8)]) = pk;
    }
    __syncthreads();

    // ---- gemm1: Zt[p][h] = sum_w P[p][w] X[h][w] ----
    f32x4 acc[8][4];
#pragma unroll
    for (int mi = 0; mi < 8; ++mi)
#pragma unroll
        for (int nj = 0; nj < 4; ++nj) acc[mi][nj] = (f32x4){0.f, 0.f, 0.f, 0.f};

#pragma unroll
    for (int ks = 0; ks < 8; ++ks) {
        const int ck = ks * 4 + lhi;
        bf16x8 bfrag[4], afrag[8];
#pragma unroll
        for (int nj = 0; nj < 4; ++nj) {
            const int r = wn + nj * 16 + l15;
            bfrag[nj] = *(const bf16x8*)(&lds[r * IMG + ((ck ^ (r & 7)) * 8)]);
        }
#pragma unroll
        for (int mi = 0; mi < 8; ++mi) {
            const int r = wm + mi * 16 + l15;
            afrag[mi] = *(const bf16x8*)(P + (size_t)r * IMG + ks * 32 + lhi * 8);
        }
#pragma unroll
        for (int mi = 0; mi < 8; ++mi)
#pragma unroll
            for (int nj = 0; nj < 4; ++nj)
                acc[mi][nj] = __builtin_amdgcn_mfma_f32_16x16x32_bf16(
                    afrag[mi], bfrag[nj], acc[mi][nj], 0, 0, 0);
    }
    __syncthreads();

    // ---- write Zt bf16 -> LDS [p][h], swizzled ----
#pragma unroll
    for (int mi = 0; mi < 8; ++mi)
#pragma unroll
        for (int nj = 0; nj < 4; ++nj)
#pragma unroll
            for (int r = 0; r < 4; ++r) {
                const int p = wm + mi * 16 + row4 + r;
                const int h = wn + nj * 16 + l15;
                lds[p * IMG + (((h >> 3) ^ (p & 7)) * 8) + (h & 7)] =
                    f2bf(acc[mi][nj][r]);
            }
    __syncthreads();

    // ---- gemm2: out[o][p] = sum_h P[o][h] Zt[p][h] ----
    f32x4 acc2[8][4];
#pragma unroll
    for (int mi = 0; mi < 8; ++mi)
#pragma unroll
        for (int nj = 0; nj < 4; ++nj) acc2[mi][nj] = (f32x4){0.f, 0.f, 0.f, 0.f};

#pragma unroll
    for (int ks = 0; ks < 8; ++ks) {
        const int ck = ks * 4 + lhi;
        bf16x8 bfrag[4], afrag[8];
#pragma unroll
        for (int nj = 0; nj < 4; ++nj) {
            const int r = wn + nj * 16 + l15;
            bfrag[nj] = *(const bf16x8*)(&lds[r * IMG + ((ck ^ (r & 7)) * 8)]);
        }
#pragma unroll
        for (int mi = 0; mi < 8; ++mi) {
            const int r = wm + mi * 16 + l15;
            afrag[mi] = *(const bf16x8*)(P + (size_t)r * IMG + ks * 32 + lhi * 8);
        }
#pragma unroll
        for (int mi = 0; mi < 8; ++mi)
#pragma unroll
            for (int nj = 0; nj < 4; ++nj)
                acc2[mi][nj] = __builtin_amdgcn_mfma_f32_16x16x32_bf16(
                    afrag[mi], bfrag[nj], acc2[mi][nj], 0, 0, 0);
    }

    // ---- store out fp32 [o][p] ----
#pragma unroll
    for (int mi = 0; mi < 8; ++mi)
#pragma unroll
        for (int nj = 0; nj < 4; ++nj)
#pragma unroll
            for (int r = 0; r < 4; ++r) {
                const int o = wm + mi * 16 + row4 + r;
                const int p = wn + nj * 16 + l15;
                outb[(size_t)o * IMG + p] = acc2[mi][nj][r];
            }
}

// ---------------------------------------------------------------------------
extern "C" void kernel_launch(void* const* d_in, const int* in_sizes, int n_in,
                              void* d_out, int out_size, void* d_ws, size_t ws_size,
                              hipStream_t stream) {
    const float* x0 = (const float*)d_in[0];
    const int* t = (const int*)d_in[1];
    float* out = (float*)d_out;

    u16* Pbf = (u16*)d_ws;  // 20*256*256 bf16 = 2.62 MB

    hipLaunchKernelGGL(build_P, dim3(IMG, TS), dim3(IMG), 0, stream, Pbf);
    hipLaunchKernelGGL(fused_pxp, dim3(64 * 3), dim3(512), 0, stream,
                       Pbf, x0, out, t);
}

// Round 3
// 145.216 us; speedup vs baseline: 1.1184x; 1.1184x over previous
//
#include <hip/hip_runtime.h>
#include <hip/hip_bf16.h>

#define IMG 256
#define TS 20

typedef unsigned short u16;
typedef __bf16 bf16x8 __attribute__((ext_vector_type(8)));
typedef float f32x4 __attribute__((ext_vector_type(4)));
typedef unsigned short ushort8 __attribute__((ext_vector_type(8)));

__device__ __forceinline__ double cc1d(double x) {
    const double A = -0.75;
    return ((A + 2.0) * x - (A + 3.0)) * x * x + 1.0;
}
__device__ __forceinline__ double cc2d(double x) {
    const double A = -0.75;
    return ((A * x - 5.0 * A) * x + 8.0 * A) * x - 4.0 * A;
}

// fp32 -> bf16 round-to-nearest-even, bit form
__device__ __forceinline__ u16 f2bf(float f) {
    unsigned u = __float_as_uint(f);
    u = u + 0x7fffu + ((u >> 16) & 1u);
    return (u16)(u >> 16);
}

// ---------------------------------------------------------------------------
// build_P2: P_0 = I; P_{i+1} = (N·B)_i · P_i  (row-gather, 4 nnz/row).
// Column-sliced: 32 blocks × 8 columns; 256 threads = one thread per row.
// fp32 double-buffered slice in LDS; one barrier per step.
// ---------------------------------------------------------------------------
#define BPC 8    // columns per block
#define BPS 12   // LDS row stride (floats): 48B rows, bank-spread, 16B-aligned
__global__ __launch_bounds__(256) void build_P2(u16* __restrict__ Pbf) {
    __shared__ __align__(16) float buf[2][IMG][BPS];
    const int col0 = blockIdx.x * BPC;
    const int o = threadIdx.x;

    // P_0 = I slice
    f32x4 n0 = (f32x4){0.f, 0.f, 0.f, 0.f};
    f32x4 n1 = (f32x4){0.f, 0.f, 0.f, 0.f};
    if (o >= col0 && o < col0 + 4) n0[o - col0] = 1.0f;
    if (o >= col0 + 4 && o < col0 + 8) n1[o - col0 - 4] = 1.0f;
    *(f32x4*)&buf[0][o][0] = n0;
    *(f32x4*)&buf[0][o][4] = n1;
    {
        ushort8 pk;
#pragma unroll
        for (int c = 0; c < 4; ++c) pk[c] = f2bf(n0[c]);
#pragma unroll
        for (int c = 0; c < 4; ++c) pk[4 + c] = f2bf(n1[c]);
        *(ushort8*)(Pbf + (size_t)o * IMG + col0) = pk;
    }

    int cur = 0;
    for (int i = 0; i < TS - 1; ++i) {
        // row o of (N·B)_i : weights + source rows (registers only)
        const int s = IMG - i;
        double xs = (o + 0.5) * (double)s / 256.0;
        int j = (int)xs;
        if (j > s - 1) j = s - 1;
        double x = (j + 0.5) * 256.0 / (double)s - 0.5;
        int i0 = (int)floor(x);
        double tt = x - (double)i0;
        float w[4] = {(float)cc2d(tt + 1.0), (float)cc1d(tt),
                      (float)cc1d(1.0 - tt), (float)cc2d(2.0 - tt)};
        int c[4];
#pragma unroll
        for (int k = 0; k < 4; ++k) c[k] = min(max(i0 - 1 + k, 0), IMG - 1);

        __syncthreads();  // buf[cur] fully written (prev step / init)
        f32x4 a0 = (f32x4){0.f, 0.f, 0.f, 0.f};
        f32x4 a1 = (f32x4){0.f, 0.f, 0.f, 0.f};
#pragma unroll
        for (int k = 0; k < 4; ++k) {
            const float wk = w[k];
            const f32x4 b0 = *(const f32x4*)&buf[cur][c[k]][0];
            const f32x4 b1 = *(const f32x4*)&buf[cur][c[k]][4];
            a0 += wk * b0;
            a1 += wk * b1;
        }
        const int nxt = cur ^ 1;
        *(f32x4*)&buf[nxt][o][0] = a0;
        *(f32x4*)&buf[nxt][o][4] = a1;

        ushort8 pk;
#pragma unroll
        for (int cc = 0; cc < 4; ++cc) pk[cc] = f2bf(a0[cc]);
#pragma unroll
        for (int cc = 0; cc < 4; ++cc) pk[4 + cc] = f2bf(a1[cc]);
        *(ushort8*)(Pbf + ((size_t)(i + 1) * IMG + o) * IMG + col0) = pk;
        cur = nxt;
    }
}

// ---------------------------------------------------------------------------
// Fused kernel: one block per (b,c) image.
//   stage:  X fp32 (global) -> bf16 LDS [h][w]   (XOR-swizzled 16B chunks)
//   gemm1:  Zt[p][h] = sum_w P[p][w] * X[h][w]    (A=P global/L2, Bt=X LDS)
//   write:  Zt bf16 -> same LDS buffer [p][h]     (swizzled)
//   gemm2:  out[o][p] = sum_h P[o][h] * Zt[p][h]  (A=P global/L2, Bt=Zt LDS)
//   epi:    per-wave LDS slab transpose -> float4 line-complete stores
// ---------------------------------------------------------------------------
#define SLAB_STRIDE 72  // floats per slab row (288B: 16B-aligned, bank-spread)
__global__ __launch_bounds__(512, 1) void fused_pxp(const u16* __restrict__ Pbf,
                                                    const float* __restrict__ X,
                                                    float* __restrict__ out,
                                                    const int* __restrict__ tarr) {
    __shared__ __align__(16) u16 lds[IMG * IMG];  // 128 KB

    const int bc = blockIdx.x;
    const int b = bc / 3;
    const int tsel = tarr[b];
    const u16* __restrict__ P = Pbf + (size_t)tsel * IMG * IMG;
    const float* __restrict__ Xb = X + (size_t)bc * IMG * IMG;
    float* __restrict__ outb = out + (size_t)bc * IMG * IMG;

    const int tid = threadIdx.x;
    const int lane = tid & 63;
    const int wave = tid >> 6;
    const int wm = (wave >> 2) * 128;
    const int wn = (wave & 3) * 64;
    const int l15 = lane & 15;
    const int lhi = lane >> 4;
    const int row4 = lhi * 4;

    // ---- stage X: fp32 -> bf16 LDS [h][w], swizzled 16B chunks ----
#pragma unroll
    for (int it = 0; it < 16; ++it) {
        const int g = it * 512 + tid;
        const int h = g >> 5;
        const int c = g & 31;
        const float* src = Xb + (size_t)h * IMG + c * 8;
        const float4 v0 = *(const float4*)(src);
        const float4 v1 = *(const float4*)(src + 4);
        ushort8 pk;
        pk[0] = f2bf(v0.x); pk[1] = f2bf(v0.y); pk[2] = f2bf(v0.z); pk[3] = f2bf(v0.w);
        pk[4] = f2bf(v1.x); pk[5] = f2bf(v1.y); pk[6] = f2bf(v1.z); pk[7] = f2bf(v1.w);
        *(ushort8*)(&lds[h * IMG + ((c ^ (h & 7)) * 8)]) = pk;
    }
    __syncthreads();

    // ---- gemm1: Zt[p][h] = sum_w P[p][w] X[h][w] ----
    f32x4 acc[8][4];
#pragma unroll
    for (int mi = 0; mi < 8; ++mi)
#pragma unroll
        for (int nj = 0; nj < 4; ++nj) acc[mi][nj] = (f32x4){0.f, 0.f, 0.f, 0.f};

#pragma unroll
    for (int ks = 0; ks < 8; ++ks) {
        const int ck = ks * 4 + lhi;
        bf16x8 bfrag[4], afrag[8];
#pragma unroll
        for (int nj = 0; nj < 4; ++nj) {
            const int r = wn + nj * 16 + l15;
            bfrag[nj] = *(const bf16x8*)(&lds[r * IMG + ((ck ^ (r & 7)) * 8)]);
        }
#pragma unroll
        for (int mi = 0; mi < 8; ++mi) {
            const int r = wm + mi * 16 + l15;
            afrag[mi] = *(const bf16x8*)(P + (size_t)r * IMG + ks * 32 + lhi * 8);
        }
#pragma unroll
        for (int mi = 0; mi < 8; ++mi)
#pragma unroll
            for (int nj = 0; nj < 4; ++nj)
                acc[mi][nj] = __builtin_amdgcn_mfma_f32_16x16x32_bf16(
                    afrag[mi], bfrag[nj], acc[mi][nj], 0, 0, 0);
    }
    __syncthreads();

    // ---- write Zt bf16 -> LDS [p][h], swizzled ----
#pragma unroll
    for (int mi = 0; mi < 8; ++mi)
#pragma unroll
        for (int nj = 0; nj < 4; ++nj)
#pragma unroll
            for (int r = 0; r < 4; ++r) {
                const int p = wm + mi * 16 + row4 + r;
                const int h = wn + nj * 16 + l15;
                lds[p * IMG + (((h >> 3) ^ (p & 7)) * 8) + (h & 7)] =
                    f2bf(acc[mi][nj][r]);
            }
    __syncthreads();

    // ---- gemm2: out[o][p] = sum_h P[o][h] Zt[p][h] ----
    f32x4 acc2[8][4];
#pragma unroll
    for (int mi = 0; mi < 8; ++mi)
#pragma unroll
        for (int nj = 0; nj < 4; ++nj) acc2[mi][nj] = (f32x4){0.f, 0.f, 0.f, 0.f};

#pragma unroll
    for (int ks = 0; ks < 8; ++ks) {
        const int ck = ks * 4 + lhi;
        bf16x8 bfrag[4], afrag[8];
#pragma unroll
        for (int nj = 0; nj < 4; ++nj) {
            const int r = wn + nj * 16 + l15;
            bfrag[nj] = *(const bf16x8*)(&lds[r * IMG + ((ck ^ (r & 7)) * 8)]);
        }
#pragma unroll
        for (int mi = 0; mi < 8; ++mi) {
            const int r = wm + mi * 16 + l15;
            afrag[mi] = *(const bf16x8*)(P + (size_t)r * IMG + ks * 32 + lhi * 8);
        }
#pragma unroll
        for (int mi = 0; mi < 8; ++mi)
#pragma unroll
            for (int nj = 0; nj < 4; ++nj)
                acc2[mi][nj] = __builtin_amdgcn_mfma_f32_16x16x32_bf16(
                    afrag[mi], bfrag[nj], acc2[mi][nj], 0, 0, 0);
    }
    __syncthreads();  // all waves done reading Zt; LDS now reusable as slabs

    // ---- epilogue: per-wave slab transpose -> coalesced float4 stores ----
    float* slabf = (float*)lds + (size_t)wave * 16 * SLAB_STRIDE;  // 4608B/wave
#pragma unroll
    for (int mi = 0; mi < 8; ++mi) {
#pragma unroll
        for (int nj = 0; nj < 4; ++nj)
#pragma unroll
            for (int r = 0; r < 4; ++r)
                slabf[(row4 + r) * SLAB_STRIDE + nj * 16 + l15] = acc2[mi][nj][r];
        // wave-internal LDS dependency; compiler inserts lgkmcnt
#pragma unroll
        for (int j = 0; j < 4; ++j) {
            const int rr = lhi + j * 4;
            const f32x4 v = *(const f32x4*)&slabf[rr * SLAB_STRIDE + l15 * 4];
            *(f32x4*)&outb[(size_t)(wm + mi * 16 + rr) * IMG + wn + l15 * 4] = v;
        }
    }
}

// ---------------------------------------------------------------------------
extern "C" void kernel_launch(void* const* d_in, const int* in_sizes, int n_in,
                              void* d_out, int out_size, void* d_ws, size_t ws_size,
                              hipStream_t stream) {
    const float* x0 = (const float*)d_in[0];
    const int* t = (const int*)d_in[1];
    float* out = (float*)d_out;

    u16* Pbf = (u16*)d_ws;  // 20*256*256 bf16 = 2.62 MB

    hipLaunchKernelGGL(build_P2, dim3(IMG / BPC), dim3(IMG), 0, stream, Pbf);
    hipLaunchKernelGGL(fused_pxp, dim3(64 * 3), dim3(512), 0, stream,
                       Pbf, x0, out, t);
}

// Round 4
// 134.311 us; speedup vs baseline: 1.2092x; 1.0812x over previous
//
#include <hip/hip_runtime.h>
#include <hip/hip_bf16.h>

#define IMG 256
#define TS 20

typedef unsigned short u16;
typedef __bf16 bf16x8 __attribute__((ext_vector_type(8)));
typedef float f32x4 __attribute__((ext_vector_type(4)));
typedef unsigned short ushort8 __attribute__((ext_vector_type(8)));

__device__ __forceinline__ double cc1d(double x) {
    const double A = -0.75;
    return ((A + 2.0) * x - (A + 3.0)) * x * x + 1.0;
}
__device__ __forceinline__ double cc2d(double x) {
    const double A = -0.75;
    return ((A * x - 5.0 * A) * x + 8.0 * A) * x - 4.0 * A;
}

// fp32 -> bf16 round-to-nearest-even, bit form
__device__ __forceinline__ u16 f2bf(float f) {
    unsigned u = __float_as_uint(f);
    u = u + 0x7fffu + ((u >> 16) & 1u);
    return (u16)(u >> 16);
}

// ---------------------------------------------------------------------------
// build_P2: P_0 = I; P_{i+1} = (N·B)_i · P_i  (row-gather, 4 nnz/row).
// Column-sliced: 32 blocks × 8 columns; 256 threads = one thread per row.
// (verified R3: ~5 µs, absmax 0.031)
// ---------------------------------------------------------------------------
#define BPC 8    // columns per block
#define BPS 12   // LDS row stride (floats)
__global__ __launch_bounds__(256) void build_P2(u16* __restrict__ Pbf) {
    __shared__ __align__(16) float buf[2][IMG][BPS];
    const int col0 = blockIdx.x * BPC;
    const int o = threadIdx.x;

    f32x4 n0 = (f32x4){0.f, 0.f, 0.f, 0.f};
    f32x4 n1 = (f32x4){0.f, 0.f, 0.f, 0.f};
    if (o >= col0 && o < col0 + 4) n0[o - col0] = 1.0f;
    if (o >= col0 + 4 && o < col0 + 8) n1[o - col0 - 4] = 1.0f;
    *(f32x4*)&buf[0][o][0] = n0;
    *(f32x4*)&buf[0][o][4] = n1;
    {
        ushort8 pk;
#pragma unroll
        for (int c = 0; c < 4; ++c) pk[c] = f2bf(n0[c]);
#pragma unroll
        for (int c = 0; c < 4; ++c) pk[4 + c] = f2bf(n1[c]);
        *(ushort8*)(Pbf + (size_t)o * IMG + col0) = pk;
    }

    int cur = 0;
    for (int i = 0; i < TS - 1; ++i) {
        const int s = IMG - i;
        double xs = (o + 0.5) * (double)s / 256.0;
        int j = (int)xs;
        if (j > s - 1) j = s - 1;
        double x = (j + 0.5) * 256.0 / (double)s - 0.5;
        int i0 = (int)floor(x);
        double tt = x - (double)i0;
        float w[4] = {(float)cc2d(tt + 1.0), (float)cc1d(tt),
                      (float)cc1d(1.0 - tt), (float)cc2d(2.0 - tt)};
        int c[4];
#pragma unroll
        for (int k = 0; k < 4; ++k) c[k] = min(max(i0 - 1 + k, 0), IMG - 1);

        __syncthreads();
        f32x4 a0 = (f32x4){0.f, 0.f, 0.f, 0.f};
        f32x4 a1 = (f32x4){0.f, 0.f, 0.f, 0.f};
#pragma unroll
        for (int k = 0; k < 4; ++k) {
            const float wk = w[k];
            a0 += wk * *(const f32x4*)&buf[cur][c[k]][0];
            a1 += wk * *(const f32x4*)&buf[cur][c[k]][4];
        }
        const int nxt = cur ^ 1;
        *(f32x4*)&buf[nxt][o][0] = a0;
        *(f32x4*)&buf[nxt][o][4] = a1;

        ushort8 pk;
#pragma unroll
        for (int cc = 0; cc < 4; ++cc) pk[cc] = f2bf(a0[cc]);
#pragma unroll
        for (int cc = 0; cc < 4; ++cc) pk[4 + cc] = f2bf(a1[cc]);
        *(ushort8*)(Pbf + ((size_t)(i + 1) * IMG + o) * IMG + col0) = pk;
        cur = nxt;
    }
}

// ---------------------------------------------------------------------------
// gemm_px: C[m,n] = sum_k A[m,k] * Bt[n,k], A = P[t[b]] (both modes).
// MODE 0 (gemm1): Bt = X[bc] fp32 (cvt on stage), C = Z[bc] bf16
//                 Z[p][h] = sum_w P[p][w] X[h][w]
// MODE 1 (gemm2): Bt = Z[bc] bf16,               C = out[bc] fp32
//                 out[o][p] = sum_h P[o][h] Z[p][h]
// 128x128 tile, 4 waves x (64x64), BK=64, mfma_f32_16x16x32_bf16.
// LDS XOR swizzle on 16B chunks (write+read involution). [R1-verified core]
// ---------------------------------------------------------------------------
template <int MODE>
__global__ __launch_bounds__(256) void gemm_px(const u16* __restrict__ Pbf,
                                               const void* __restrict__ BtSrc,
                                               void* __restrict__ Cout,
                                               const int* __restrict__ tarr) {
    __shared__ __align__(16) u16 ldsA[128 * 64];
    __shared__ __align__(16) u16 ldsB[128 * 64];

    const int bc = blockIdx.y;
    const int tsel = tarr[bc / 3];
    const u16* __restrict__ A = Pbf + (size_t)tsel * IMG * IMG;

    const int tile_m = (blockIdx.x >> 1) * 128;
    const int tile_n = (blockIdx.x & 1) * 128;
    const int tid = threadIdx.x;
    const int lane = tid & 63;
    const int wave = tid >> 6;
    const int wm = (wave >> 1) * 64;
    const int wn = (wave & 1) * 64;

    f32x4 acc[4][4];
#pragma unroll
    for (int i = 0; i < 4; ++i)
#pragma unroll
        for (int j = 0; j < 4; ++j) acc[i][j] = (f32x4){0.f, 0.f, 0.f, 0.f};

    for (int kt = 0; kt < 4; ++kt) {
        __syncthreads();
#pragma unroll
        for (int q = 0; q < 4; ++q) {
            const int id = q * 256 + tid;
            const int row = id >> 3;
            const int kb = id & 7;
            const int kswz = kb ^ (row & 7);
            const uint4 av = *(const uint4*)(A + (size_t)(tile_m + row) * IMG + kt * 64 + kb * 8);
            *(uint4*)(ldsA + row * 64 + kswz * 8) = av;
            if (MODE == 0) {
                const float* xs = (const float*)BtSrc + (size_t)bc * IMG * IMG +
                                  (size_t)(tile_n + row) * IMG + kt * 64 + kb * 8;
                const float4 v0 = *(const float4*)(xs);
                const float4 v1 = *(const float4*)(xs + 4);
                ushort8 pk;
                pk[0] = f2bf(v0.x); pk[1] = f2bf(v0.y); pk[2] = f2bf(v0.z); pk[3] = f2bf(v0.w);
                pk[4] = f2bf(v1.x); pk[5] = f2bf(v1.y); pk[6] = f2bf(v1.z); pk[7] = f2bf(v1.w);
                *(ushort8*)(ldsB + row * 64 + kswz * 8) = pk;
            } else {
                const u16* zs = (const u16*)BtSrc + (size_t)bc * IMG * IMG +
                                (size_t)(tile_n + row) * IMG + kt * 64 + kb * 8;
                const uint4 bv = *(const uint4*)zs;
                *(uint4*)(ldsB + row * 64 + kswz * 8) = bv;
            }
        }
        __syncthreads();
#pragma unroll
        for (int kk = 0; kk < 2; ++kk) {
            const int kb_log = kk * 4 + (lane >> 4);
            bf16x8 afrag[4], bfrag[4];
#pragma unroll
            for (int mi = 0; mi < 4; ++mi) {
                const int r = wm + mi * 16 + (lane & 15);
                afrag[mi] = *(const bf16x8*)(ldsA + r * 64 + ((kb_log ^ (r & 7)) * 8));
            }
#pragma unroll
            for (int nj = 0; nj < 4; ++nj) {
                const int r = wn + nj * 16 + (lane & 15);
                bfrag[nj] = *(const bf16x8*)(ldsB + r * 64 + ((kb_log ^ (r & 7)) * 8));
            }
#pragma unroll
            for (int mi = 0; mi < 4; ++mi)
#pragma unroll
                for (int nj = 0; nj < 4; ++nj)
                    acc[mi][nj] = __builtin_amdgcn_mfma_f32_16x16x32_bf16(
                        afrag[mi], bfrag[nj], acc[mi][nj], 0, 0, 0);
        }
    }

    const int col0 = lane & 15;
    const int row4 = (lane >> 4) * 4;
    if (MODE == 0) {
        u16* C = (u16*)Cout + (size_t)bc * IMG * IMG;
#pragma unroll
        for (int mi = 0; mi < 4; ++mi)
#pragma unroll
            for (int nj = 0; nj < 4; ++nj)
#pragma unroll
                for (int r = 0; r < 4; ++r) {
                    const int ro = tile_m + wm + mi * 16 + row4 + r;
                    const int co = tile_n + wn + nj * 16 + col0;
                    C[(size_t)ro * IMG + co] = f2bf(acc[mi][nj][r]);
                }
    } else {
        float* C = (float*)Cout + (size_t)bc * IMG * IMG;
#pragma unroll
        for (int mi = 0; mi < 4; ++mi)
#pragma unroll
            for (int nj = 0; nj < 4; ++nj)
#pragma unroll
                for (int r = 0; r < 4; ++r) {
                    const int ro = tile_m + wm + mi * 16 + row4 + r;
                    const int co = tile_n + wn + nj * 16 + col0;
                    C[(size_t)ro * IMG + co] = acc[mi][nj][r];
                }
    }
}

// ---------------------------------------------------------------------------
extern "C" void kernel_launch(void* const* d_in, const int* in_sizes, int n_in,
                              void* d_out, int out_size, void* d_ws, size_t ws_size,
                              hipStream_t stream) {
    const float* x0 = (const float*)d_in[0];
    const int* t = (const int*)d_in[1];
    float* out = (float*)d_out;

    // ws: P (20*256*256 bf16 = 2.62 MB) | Z (192*256*256 bf16 = 25.2 MB)
    u16* Pbf = (u16*)d_ws;
    u16* Z = (u16*)((char*)d_ws + (size_t)TS * IMG * IMG * sizeof(u16));

    hipLaunchKernelGGL(build_P2, dim3(IMG / BPC), dim3(IMG), 0, stream, Pbf);
    hipLaunchKernelGGL((gemm_px<0>), dim3(4, 192), dim3(256), 0, stream,
                       Pbf, (const void*)x0, (void*)Z, t);
    hipLaunchKernelGGL((gemm_px<1>), dim3(4, 192), dim3(256), 0, stream,
                       Pbf, (const void*)Z, (void*)out, t);
}

// Round 5
// 132.925 us; speedup vs baseline: 1.2218x; 1.0104x over previous
//
#include <hip/hip_runtime.h>
#include <hip/hip_bf16.h>

#define IMG 256
#define TS 20

typedef unsigned short u16;
typedef __bf16 bf16x8 __attribute__((ext_vector_type(8)));
typedef float f32x4 __attribute__((ext_vector_type(4)));
typedef unsigned short ushort8 __attribute__((ext_vector_type(8)));

__device__ __forceinline__ float cc1f(float x) {
    const float A = -0.75f;
    return ((A + 2.0f) * x - (A + 3.0f)) * x * x + 1.0f;
}
__device__ __forceinline__ float cc2f(float x) {
    const float A = -0.75f;
    return ((A * x - 5.0f * A) * x + 8.0f * A) * x - 4.0f * A;
}

// fp32 -> bf16 round-to-nearest-even, bit form
__device__ __forceinline__ u16 f2bf(float f) {
    unsigned u = __float_as_uint(f);
    u = u + 0x7fffu + ((u >> 16) & 1u);
    return (u16)(u >> 16);
}

// ---------------------------------------------------------------------------
// build_P2: P_0 = I; P_{i+1} = (N·B)_i · P_i  (row-gather, 4 nnz/row).
// Column-sliced: 32 blocks × 8 columns; 256 threads = one thread per row.
// Fully unrolled step loop (s = IMG-i is a literal per copy -> divides fold);
// f32 weight math (x-granularity >= 1/512 >> f32 eps -> floors exact).
// ---------------------------------------------------------------------------
#define BPC 8    // columns per block
#define BPS 12   // LDS row stride (floats)
__global__ __launch_bounds__(256) void build_P2(u16* __restrict__ Pbf) {
    __shared__ __align__(16) float buf[2][IMG][BPS];
    const int col0 = blockIdx.x * BPC;
    const int o = threadIdx.x;

    f32x4 n0 = (f32x4){0.f, 0.f, 0.f, 0.f};
    f32x4 n1 = (f32x4){0.f, 0.f, 0.f, 0.f};
    if (o >= col0 && o < col0 + 4) n0[o - col0] = 1.0f;
    if (o >= col0 + 4 && o < col0 + 8) n1[o - col0 - 4] = 1.0f;
    *(f32x4*)&buf[0][o][0] = n0;
    *(f32x4*)&buf[0][o][4] = n1;
    {
        ushort8 pk;
#pragma unroll
        for (int c = 0; c < 4; ++c) pk[c] = f2bf(n0[c]);
#pragma unroll
        for (int c = 0; c < 4; ++c) pk[4 + c] = f2bf(n1[c]);
        *(ushort8*)(Pbf + (size_t)o * IMG + col0) = pk;
    }

    int cur = 0;
#pragma unroll
    for (int i = 0; i < TS - 1; ++i) {
        const int s = IMG - i;  // literal per unrolled copy
        // nearest-exact: j = clip(floor((o+0.5)*s/256), 0, s-1)
        // (o+0.5)*s exact in f32 (numerator < 2^24); /256 exact (pow2)
        float xs = (o + 0.5f) * (float)s * (1.0f / 256.0f);
        int j = (int)xs;
        if (j > s - 1) j = s - 1;
        // bicubic: x = (j+0.5)*256/s - 0.5 ; granularity 1/(2s) >= 1/512
        float x = (j + 0.5f) * (256.0f / (float)s) - 0.5f;
        float fl = floorf(x);
        int i0 = (int)fl;
        float tt = x - fl;
        float w[4] = {cc2f(tt + 1.0f), cc1f(tt), cc1f(1.0f - tt), cc2f(2.0f - tt)};
        int c[4];
#pragma unroll
        for (int k = 0; k < 4; ++k) c[k] = min(max(i0 - 1 + k, 0), IMG - 1);

        __syncthreads();
        f32x4 a0 = (f32x4){0.f, 0.f, 0.f, 0.f};
        f32x4 a1 = (f32x4){0.f, 0.f, 0.f, 0.f};
#pragma unroll
        for (int k = 0; k < 4; ++k) {
            const float wk = w[k];
            a0 += wk * *(const f32x4*)&buf[cur][c[k]][0];
            a1 += wk * *(const f32x4*)&buf[cur][c[k]][4];
        }
        const int nxt = cur ^ 1;
        *(f32x4*)&buf[nxt][o][0] = a0;
        *(f32x4*)&buf[nxt][o][4] = a1;

        ushort8 pk;
#pragma unroll
        for (int cc = 0; cc < 4; ++cc) pk[cc] = f2bf(a0[cc]);
#pragma unroll
        for (int cc = 0; cc < 4; ++cc) pk[4 + cc] = f2bf(a1[cc]);
        *(ushort8*)(Pbf + ((size_t)(i + 1) * IMG + o) * IMG + col0) = pk;
        cur = nxt;
    }
}

// ---------------------------------------------------------------------------
// gemm_px: C[m,n] = sum_k A[m,k] * Bt[n,k], A = P[t[b]] (both modes).
// MODE 0 (gemm1): Bt = X[bc] fp32 (cvt on stage), C = Z[bc] bf16
// MODE 1 (gemm2): Bt = Z[bc] bf16,               C = out[bc] fp32
// 128x128 tile, 4 waves x (64x64), BK=64, mfma_f32_16x16x32_bf16.
// grid(192, 4): the 4 tile-blocks of one image are 192 apart in linear
// dispatch order -> same XCD -> A/Bt half-tile re-reads are L2-local.
// ---------------------------------------------------------------------------
template <int MODE>
__global__ __launch_bounds__(256) void gemm_px(const u16* __restrict__ Pbf,
                                               const void* __restrict__ BtSrc,
                                               void* __restrict__ Cout,
                                               const int* __restrict__ tarr) {
    __shared__ __align__(16) u16 ldsA[128 * 64];
    __shared__ __align__(16) u16 ldsB[128 * 64];

    const int bc = blockIdx.x;
    const int tsel = tarr[bc / 3];
    const u16* __restrict__ A = Pbf + (size_t)tsel * IMG * IMG;

    const int tile_m = (blockIdx.y >> 1) * 128;
    const int tile_n = (blockIdx.y & 1) * 128;
    const int tid = threadIdx.x;
    const int lane = tid & 63;
    const int wave = tid >> 6;
    const int wm = (wave >> 1) * 64;
    const int wn = (wave & 1) * 64;

    f32x4 acc[4][4];
#pragma unroll
    for (int i = 0; i < 4; ++i)
#pragma unroll
        for (int j = 0; j < 4; ++j) acc[i][j] = (f32x4){0.f, 0.f, 0.f, 0.f};

    for (int kt = 0; kt < 4; ++kt) {
        __syncthreads();
#pragma unroll
        for (int q = 0; q < 4; ++q) {
            const int id = q * 256 + tid;
            const int row = id >> 3;
            const int kb = id & 7;
            const int kswz = kb ^ (row & 7);
            const uint4 av = *(const uint4*)(A + (size_t)(tile_m + row) * IMG + kt * 64 + kb * 8);
            *(uint4*)(ldsA + row * 64 + kswz * 8) = av;
            if (MODE == 0) {
                const float* xs = (const float*)BtSrc + (size_t)bc * IMG * IMG +
                                  (size_t)(tile_n + row) * IMG + kt * 64 + kb * 8;
                const float4 v0 = *(const float4*)(xs);
                const float4 v1 = *(const float4*)(xs + 4);
                ushort8 pk;
                pk[0] = f2bf(v0.x); pk[1] = f2bf(v0.y); pk[2] = f2bf(v0.z); pk[3] = f2bf(v0.w);
                pk[4] = f2bf(v1.x); pk[5] = f2bf(v1.y); pk[6] = f2bf(v1.z); pk[7] = f2bf(v1.w);
                *(ushort8*)(ldsB + row * 64 + kswz * 8) = pk;
            } else {
                const u16* zs = (const u16*)BtSrc + (size_t)bc * IMG * IMG +
                                (size_t)(tile_n + row) * IMG + kt * 64 + kb * 8;
                const uint4 bv = *(const uint4*)zs;
                *(uint4*)(ldsB + row * 64 + kswz * 8) = bv;
            }
        }
        __syncthreads();
#pragma unroll
        for (int kk = 0; kk < 2; ++kk) {
            const int kb_log = kk * 4 + (lane >> 4);
            bf16x8 afrag[4], bfrag[4];
#pragma unroll
            for (int mi = 0; mi < 4; ++mi) {
                const int r = wm + mi * 16 + (lane & 15);
                afrag[mi] = *(const bf16x8*)(ldsA + r * 64 + ((kb_log ^ (r & 7)) * 8));
            }
#pragma unroll
            for (int nj = 0; nj < 4; ++nj) {
                const int r = wn + nj * 16 + (lane & 15);
                bfrag[nj] = *(const bf16x8*)(ldsB + r * 64 + ((kb_log ^ (r & 7)) * 8));
            }
#pragma unroll
            for (int mi = 0; mi < 4; ++mi)
#pragma unroll
                for (int nj = 0; nj < 4; ++nj)
                    acc[mi][nj] = __builtin_amdgcn_mfma_f32_16x16x32_bf16(
                        afrag[mi], bfrag[nj], acc[mi][nj], 0, 0, 0);
        }
    }

    const int col0 = lane & 15;
    const int row4 = (lane >> 4) * 4;
    if (MODE == 0) {
        u16* C = (u16*)Cout + (size_t)bc * IMG * IMG;
#pragma unroll
        for (int mi = 0; mi < 4; ++mi)
#pragma unroll
            for (int nj = 0; nj < 4; ++nj)
#pragma unroll
                for (int r = 0; r < 4; ++r) {
                    const int ro = tile_m + wm + mi * 16 + row4 + r;
                    const int co = tile_n + wn + nj * 16 + col0;
                    C[(size_t)ro * IMG + co] = f2bf(acc[mi][nj][r]);
                }
    } else {
        float* C = (float*)Cout + (size_t)bc * IMG * IMG;
#pragma unroll
        for (int mi = 0; mi < 4; ++mi)
#pragma unroll
            for (int nj = 0; nj < 4; ++nj)
#pragma unroll
                for (int r = 0; r < 4; ++r) {
                    const int ro = tile_m + wm + mi * 16 + row4 + r;
                    const int co = tile_n + wn + nj * 16 + col0;
                    C[(size_t)ro * IMG + co] = acc[mi][nj][r];
                }
    }
}

// ---------------------------------------------------------------------------
extern "C" void kernel_launch(void* const* d_in, const int* in_sizes, int n_in,
                              void* d_out, int out_size, void* d_ws, size_t ws_size,
                              hipStream_t stream) {
    const float* x0 = (const float*)d_in[0];
    const int* t = (const int*)d_in[1];
    float* out = (float*)d_out;

    // ws: P (20*256*256 bf16 = 2.62 MB) | Z (192*256*256 bf16 = 25.2 MB)
    u16* Pbf = (u16*)d_ws;
    u16* Z = (u16*)((char*)d_ws + (size_t)TS * IMG * IMG * sizeof(u16));

    hipLaunchKernelGGL(build_P2, dim3(IMG / BPC), dim3(IMG), 0, stream, Pbf);
    hipLaunchKernelGGL((gemm_px<0>), dim3(192, 4), dim3(256), 0, stream,
                       Pbf, (const void*)x0, (void*)Z, t);
    hipLaunchKernelGGL((gemm_px<1>), dim3(192, 4), dim3(256), 0, stream,
                       Pbf, (const void*)Z, (void*)out, t);
}